// Round 1
// baseline (784.360 us; speedup 1.0000x reference)
//
#include <hip/hip_runtime.h>
#include <hip/hip_bf16.h>

typedef __attribute__((ext_vector_type(8))) short short8;
typedef __attribute__((ext_vector_type(8))) unsigned short ushort8;
typedef __attribute__((ext_vector_type(4))) float f32x4;

#define MFMA16(a, b, c) __builtin_amdgcn_mfma_f32_16x16x32_bf16((a), (b), (c), 0, 0, 0)

static constexpr int N_CTX = 4096;
static constexpr int DIM = 64;
static constexpr int QBLK = 64;
static constexpr int KVB = 64;

__device__ __forceinline__ unsigned short f2bf(float f) {
  union { __hip_bfloat16 h; unsigned short u; } cv;
  cv.h = __float2bfloat16(f);
  return cv.u;
}
__device__ __forceinline__ float bf2f(unsigned short u) {
  union { unsigned int i; float f; } cv;
  cv.i = ((unsigned int)u) << 16;
  return cv.f;
}

// 4 waves / block. Wave w owns Q rows [qb*64 + w*16, +16).
// LDS tiles are bf16 with 16B-chunk XOR swizzle: chunk ^= (row & 7).
__global__ __launch_bounds__(256, 4) void fa_fwd(
    const float* __restrict__ Q, const float* __restrict__ K,
    const float* __restrict__ V, float* __restrict__ O) {
  __shared__ unsigned short K_lds[KVB * DIM];    // [kv][d]   swizzled rows (128B)
  __shared__ unsigned short V_lds[DIM * KVB];    // [d][kv]   transposed, swizzled
  __shared__ unsigned short P_lds[4][16 * KVB];  // per-wave [qi][kv], swizzled

  const int tid = threadIdx.x;
  const int wave = tid >> 6;
  const int lane = tid & 63;
  const int g = lane >> 4;   // 0..3
  const int li = lane & 15;  // 0..15

  const size_t bh = blockIdx.y;
  const int qb = blockIdx.x;

  const float* Qb = Q + bh * N_CTX * DIM;
  const float* Kb = K + bh * N_CTX * DIM;
  const float* Vb = V + bh * N_CTX * DIM;
  float* Ob = O + bh * N_CTX * DIM;

  // ---- Q fragments in registers; fold the full 1/64 scale into Q (exact pow2) ----
  short8 aq0, aq1;
  {
    const float* qr = Qb + (size_t)(qb * QBLK + wave * 16 + li) * DIM;
    f32x4 q0 = *(const f32x4*)(qr + g * 8);
    f32x4 q1 = *(const f32x4*)(qr + g * 8 + 4);
    f32x4 q2 = *(const f32x4*)(qr + 32 + g * 8);
    f32x4 q3 = *(const f32x4*)(qr + 32 + g * 8 + 4);
    const float sc = 1.0f / 64.0f;
#pragma unroll
    for (int j = 0; j < 4; ++j) {
      aq0[j] = (short)f2bf(q0[j] * sc);
      aq0[j + 4] = (short)f2bf(q1[j] * sc);
      aq1[j] = (short)f2bf(q2[j] * sc);
      aq1[j + 4] = (short)f2bf(q3[j] * sc);
    }
  }

  f32x4 acc[4] = {{0.f, 0.f, 0.f, 0.f}, {0.f, 0.f, 0.f, 0.f},
                  {0.f, 0.f, 0.f, 0.f}, {0.f, 0.f, 0.f, 0.f}};
  float m_st[4] = {-1e30f, -1e30f, -1e30f, -1e30f};
  float l_st[4] = {0.f, 0.f, 0.f, 0.f};

  for (int t = 0; t < N_CTX / KVB; ++t) {
    __syncthreads();  // previous tile's LDS reads complete before overwrite
    {
      // wave w stages 16-column group [w*16, +16) of the 64x64 K/V tiles.
      const float* kr = Kb + ((size_t)t * KVB + lane) * DIM + wave * 16;
      const float* vr = Vb + ((size_t)t * KVB + lane) * DIM + wave * 16;
      f32x4 k0 = *(const f32x4*)(kr + 0);
      f32x4 k1 = *(const f32x4*)(kr + 4);
      f32x4 k2 = *(const f32x4*)(kr + 8);
      f32x4 k3 = *(const f32x4*)(kr + 12);
      f32x4 v0 = *(const f32x4*)(vr + 0);
      f32x4 v1 = *(const f32x4*)(vr + 4);
      f32x4 v2 = *(const f32x4*)(vr + 8);
      f32x4 v3 = *(const f32x4*)(vr + 12);

      ushort8 kk0, kk1;
#pragma unroll
      for (int j = 0; j < 4; ++j) {
        kk0[j] = f2bf(k0[j]);
        kk0[j + 4] = f2bf(k1[j]);
        kk1[j] = f2bf(k2[j]);
        kk1[j + 4] = f2bf(k3[j]);
      }
      char* kp = (char*)K_lds + lane * 128;
      *(ushort8*)(kp + (((wave * 2 + 0) ^ (lane & 7)) * 16)) = kk0;
      *(ushort8*)(kp + (((wave * 2 + 1) ^ (lane & 7)) * 16)) = kk1;

      float vf[16];
#pragma unroll
      for (int j = 0; j < 4; ++j) {
        vf[j] = v0[j];
        vf[j + 4] = v1[j];
        vf[j + 8] = v2[j];
        vf[j + 12] = v3[j];
      }
#pragma unroll
      for (int j = 0; j < 16; ++j) {
        const int d = wave * 16 + j;  // conflict-free: per instr, fixed d, kv=lane
        *(unsigned short*)((char*)V_lds + d * 128 +
                           (((lane >> 3) ^ (d & 7)) * 16) + (lane & 7) * 2) =
            f2bf(vf[j]);
      }
    }
    __syncthreads();

    // ---- S = Q·K^T  (4 col-tiles x 2 k-chunks) ----
    f32x4 s[4];
#pragma unroll
    for (int ct = 0; ct < 4; ++ct) {
      const int krow = ct * 16 + li;
      const char* kp = (const char*)K_lds + krow * 128;
      short8 b0 = *(const short8*)(kp + ((g ^ (krow & 7)) * 16));
      short8 b1 = *(const short8*)(kp + (((4 + g) ^ (krow & 7)) * 16));
      f32x4 z = {0.f, 0.f, 0.f, 0.f};
      z = MFMA16(aq0, b0, z);
      z = MFMA16(aq1, b1, z);
      s[ct] = z;
    }

    // ---- online softmax over the 64 kv columns; P (bf16-rounded) -> LDS ----
    float alpha[4];
#pragma unroll
    for (int r = 0; r < 4; ++r) {
      float mx = fmaxf(fmaxf(s[0][r], s[1][r]), fmaxf(s[2][r], s[3][r]));
      mx = fmaxf(mx, __shfl_xor(mx, 1));
      mx = fmaxf(mx, __shfl_xor(mx, 2));
      mx = fmaxf(mx, __shfl_xor(mx, 4));
      mx = fmaxf(mx, __shfl_xor(mx, 8));
      const float mn = fmaxf(m_st[r], mx);
      alpha[r] = __expf(m_st[r] - mn);
      m_st[r] = mn;
      const int prow = g * 4 + r;
      float ps = 0.f;
#pragma unroll
      for (int ct = 0; ct < 4; ++ct) {
        const unsigned short u = f2bf(__expf(s[ct][r] - mn));
        const int col = ct * 16 + li;
        *(unsigned short*)((char*)P_lds[wave] + prow * 128 +
                           (((col >> 3) ^ (prow & 7)) * 16) + (col & 7) * 2) = u;
        ps += bf2f(u);  // sum the ROUNDED P so numerator/denominator match
      }
      ps += __shfl_xor(ps, 1);
      ps += __shfl_xor(ps, 2);
      ps += __shfl_xor(ps, 4);
      ps += __shfl_xor(ps, 8);
      l_st[r] = alpha[r] * l_st[r] + ps;
    }
#pragma unroll
    for (int dt = 0; dt < 4; ++dt) {
#pragma unroll
      for (int r = 0; r < 4; ++r) acc[dt][r] *= alpha[r];
    }

    // ---- O += P·V  (A = P from per-wave LDS, B = V^T tile) ----
    const char* pp = (const char*)P_lds[wave] + li * 128;
    short8 pa0 = *(const short8*)(pp + ((g ^ (li & 7)) * 16));
    short8 pa1 = *(const short8*)(pp + (((4 + g) ^ (li & 7)) * 16));
#pragma unroll
    for (int dt = 0; dt < 4; ++dt) {
      const int d = dt * 16 + li;
      const char* vp = (const char*)V_lds + d * 128;
      short8 b0 = *(const short8*)(vp + ((g ^ (d & 7)) * 16));
      short8 b1 = *(const short8*)(vp + (((4 + g) ^ (d & 7)) * 16));
      acc[dt] = MFMA16(pa0, b0, acc[dt]);
      acc[dt] = MFMA16(pa1, b1, acc[dt]);
    }
  }

  // ---- epilogue: O / max(l, eps) ----
#pragma unroll
  for (int r = 0; r < 4; ++r) {
    const float inv = 1.0f / fmaxf(l_st[r], 1e-6f);
    float* orow = Ob + (size_t)(qb * QBLK + wave * 16 + g * 4 + r) * DIM + li;
#pragma unroll
    for (int dt = 0; dt < 4; ++dt) orow[dt * 16] = acc[dt][r] * inv;
  }
}

extern "C" void kernel_launch(void* const* d_in, const int* in_sizes, int n_in,
                              void* d_out, int out_size, void* d_ws, size_t ws_size,
                              hipStream_t stream) {
  const float* q = (const float*)d_in[0];
  const float* k = (const float*)d_in[1];
  const float* v = (const float*)d_in[2];
  float* o = (float*)d_out;
  const int bh = in_sizes[0] / (N_CTX * DIM);  // B*H = 32
  dim3 grid(N_CTX / QBLK, bh);
  hipLaunchKernelGGL(fa_fwd, grid, dim3(256), 0, stream, q, k, v, o);
}

// Round 3
// 439.178 us; speedup vs baseline: 1.7860x; 1.7860x over previous
//
#include <hip/hip_runtime.h>
#include <hip/hip_bf16.h>

typedef __attribute__((ext_vector_type(8))) short short8;
typedef __attribute__((ext_vector_type(8))) unsigned short ushort8;
typedef __attribute__((ext_vector_type(4))) unsigned short usv4;
typedef __attribute__((ext_vector_type(4))) float f32x4;

#define MFMA16(a, b, c) __builtin_amdgcn_mfma_f32_16x16x32_bf16((a), (b), (c), 0, 0, 0)

static constexpr int N_CTX = 4096;
static constexpr int DIM = 64;
static constexpr int QBLK = 128;  // 8 waves x 16 rows
static constexpr int KVB = 64;
static constexpr int NT = N_CTX / KVB;

__device__ __forceinline__ unsigned short f2bf(float f) {
  union { __hip_bfloat16 h; unsigned short u; } cv;
  cv.h = __float2bfloat16(f);
  return cv.u;
}
__device__ __forceinline__ float bf2f(unsigned short u) {
  union { unsigned int i; float f; } cv;
  cv.i = ((unsigned int)u) << 16;
  return cv.f;
}

// 8 waves. Wave w owns Q rows [qb*128 + w*16, +16).
// S^T via mfma(A=K, B=Q): softmax is in-lane (q = li domain).
// LDS bf16 tiles, 16B-chunk XOR swizzle: chunk ^= (row & 7).
__global__ __launch_bounds__(512, 4) void fa_fwd(
    const float* __restrict__ Q, const float* __restrict__ K,
    const float* __restrict__ V, float* __restrict__ O) {
  __shared__ unsigned short K_lds[KVB * DIM];    // [kv][d]
  __shared__ unsigned short V_lds[DIM * KVB];    // [d][kv] transposed
  __shared__ unsigned short P_lds[8][16 * KVB];  // per-wave [q][kv]

  const int tid = threadIdx.x;
  const int wave = tid >> 6;
  const int lane = tid & 63;
  const int g = lane >> 4;   // 0..3
  const int li = lane & 15;  // 0..15
  const int sr = tid >> 3;   // staging row 0..63
  const int sc = tid & 7;    // staging 8-col chunk 0..7

  const size_t bh = blockIdx.y;
  const int qb = blockIdx.x;
  const float* Qb = Q + bh * N_CTX * DIM;
  const float* Kb = K + bh * N_CTX * DIM;
  const float* Vb = V + bh * N_CTX * DIM;
  float* Ob = O + bh * N_CTX * DIM;

  // ---- Q fragments (B-operand layout == A layout); fold 1/64 scale in ----
  short8 aq0, aq1;
  {
    const float* qr = Qb + (size_t)(qb * QBLK + wave * 16 + li) * DIM;
    f32x4 q0 = *(const f32x4*)(qr + g * 8);
    f32x4 q1 = *(const f32x4*)(qr + g * 8 + 4);
    f32x4 q2 = *(const f32x4*)(qr + 32 + g * 8);
    f32x4 q3 = *(const f32x4*)(qr + 32 + g * 8 + 4);
    const float scale = 1.0f / 64.0f;
#pragma unroll
    for (int j = 0; j < 4; ++j) {
      aq0[j] = (short)f2bf(q0[j] * scale);
      aq0[j + 4] = (short)f2bf(q1[j] * scale);
      aq1[j] = (short)f2bf(q2[j] * scale);
      aq1[j + 4] = (short)f2bf(q3[j] * scale);
    }
  }

  f32x4 acc[4] = {{0.f, 0.f, 0.f, 0.f}, {0.f, 0.f, 0.f, 0.f},
                  {0.f, 0.f, 0.f, 0.f}, {0.f, 0.f, 0.f, 0.f}};
  float m_st = -1e30f;  // per q = li (uniform across g groups)
  float l_st = 0.f;

  // ---- prologue: prefetch tile 0 into registers ----
  const float* kp0 = Kb + (size_t)sr * DIM + sc * 8;
  const float* vp0 = Vb + (size_t)sr * DIM + sc * 8;
  f32x4 kf0 = *(const f32x4*)kp0, kf1 = *(const f32x4*)(kp0 + 4);
  f32x4 vf0 = *(const f32x4*)vp0, vf1 = *(const f32x4*)(vp0 + 4);

  for (int t = 0; t < NT; ++t) {
    // ---- stage tile t from prefetch registers ----
    {
      ushort8 kk;
#pragma unroll
      for (int j = 0; j < 4; ++j) {
        kk[j] = f2bf(kf0[j]);
        kk[j + 4] = f2bf(kf1[j]);
      }
      *(ushort8*)((char*)K_lds + sr * 128 + ((sc ^ (sr & 7)) * 16)) = kk;
      float vv[8] = {vf0[0], vf0[1], vf0[2], vf0[3],
                     vf1[0], vf1[1], vf1[2], vf1[3]};
#pragma unroll
      for (int j = 0; j < 8; ++j) {
        const int d = sc * 8 + j;
        *(unsigned short*)((char*)V_lds + d * 128 +
                           (((sr >> 3) ^ (d & 7)) * 16) + (sr & 7) * 2) =
            f2bf(vv[j]);
      }
    }
    __syncthreads();

    // ---- issue prefetch for tile t+1 (completes under compute) ----
    if (t + 1 < NT) {
      const float* kp = Kb + ((size_t)(t + 1) * KVB + sr) * DIM + sc * 8;
      const float* vp = Vb + ((size_t)(t + 1) * KVB + sr) * DIM + sc * 8;
      kf0 = *(const f32x4*)kp;
      kf1 = *(const f32x4*)(kp + 4);
      vf0 = *(const f32x4*)vp;
      vf1 = *(const f32x4*)(vp + 4);
    }

    // ---- S^T = K·Q^T : lane holds S[q=li][kv=16*ct+4*g+r] ----
    f32x4 s[4];
#pragma unroll
    for (int ct = 0; ct < 4; ++ct) {
      const int krow = ct * 16 + li;
      const char* kp2 = (const char*)K_lds + krow * 128;
      short8 b0 = *(const short8*)(kp2 + ((g ^ (krow & 7)) * 16));
      short8 b1 = *(const short8*)(kp2 + (((4 + g) ^ (krow & 7)) * 16));
      f32x4 z = {0.f, 0.f, 0.f, 0.f};
      z = MFMA16(b0, aq0, z);
      z = MFMA16(b1, aq1, z);
      s[ct] = z;
    }

    // ---- in-lane online softmax (q = li) ----
    float mx = s[0][0];
#pragma unroll
    for (int ct = 0; ct < 4; ++ct)
#pragma unroll
      for (int r = 0; r < 4; ++r) mx = fmaxf(mx, s[ct][r]);
    mx = fmaxf(mx, __shfl_xor(mx, 16));
    mx = fmaxf(mx, __shfl_xor(mx, 32));
    const float mn = fmaxf(m_st, mx);
    const float alpha = __expf(m_st - mn);
    m_st = mn;

    float ps = 0.f;
#pragma unroll
    for (int ct = 0; ct < 4; ++ct) {
      usv4 u;
#pragma unroll
      for (int r = 0; r < 4; ++r) {
        const unsigned short uu = f2bf(__expf(s[ct][r] - mn));
        u[r] = uu;
        ps += bf2f(uu);  // sum ROUNDED P so numerator/denominator match
      }
      // kv = 16*ct + 4*g + r -> chunk = 2*ct + (g>>1), byte-in-chunk 8*(g&1)+2r
      *(usv4*)((char*)P_lds[wave] + li * 128 +
               (((2 * ct + (g >> 1)) ^ (li & 7)) * 16) + 8 * (g & 1)) = u;
    }
    ps += __shfl_xor(ps, 16);
    ps += __shfl_xor(ps, 32);
    l_st = alpha * l_st + ps;

    // rescale acc: need alpha for q rows g*4+r (it lives at lane with li=g*4+r)
    float ar[4];
#pragma unroll
    for (int r = 0; r < 4; ++r) ar[r] = __shfl(alpha, (lane & 48) | (g * 4 + r));
#pragma unroll
    for (int dt = 0; dt < 4; ++dt)
#pragma unroll
      for (int r = 0; r < 4; ++r) acc[dt][r] *= ar[r];

    // ---- O += P·V  (A = P rows q=li, B = V^T tile) ----
    const char* pp = (const char*)P_lds[wave] + li * 128;
    short8 pa0 = *(const short8*)(pp + ((g ^ (li & 7)) * 16));
    short8 pa1 = *(const short8*)(pp + (((4 + g) ^ (li & 7)) * 16));
#pragma unroll
    for (int dt = 0; dt < 4; ++dt) {
      const int d = dt * 16 + li;
      const char* vp2 = (const char*)V_lds + d * 128;
      short8 b0 = *(const short8*)(vp2 + ((g ^ (d & 7)) * 16));
      short8 b1 = *(const short8*)(vp2 + (((4 + g) ^ (d & 7)) * 16));
      acc[dt] = MFMA16(pa0, b0, acc[dt]);
      acc[dt] = MFMA16(pa1, b1, acc[dt]);
    }
    __syncthreads();
  }

  // ---- epilogue: O / max(l, eps); l lives at lane with li = q row ----
  float lr[4];
#pragma unroll
  for (int r = 0; r < 4; ++r) lr[r] = __shfl(l_st, (lane & 48) | (g * 4 + r));
#pragma unroll
  for (int r = 0; r < 4; ++r) {
    const float inv = 1.0f / fmaxf(lr[r], 1e-6f);
    float* orow = Ob + (size_t)(qb * QBLK + wave * 16 + g * 4 + r) * DIM + li;
#pragma unroll
    for (int dt = 0; dt < 4; ++dt) orow[dt * 16] = acc[dt][r] * inv;
  }
}

extern "C" void kernel_launch(void* const* d_in, const int* in_sizes, int n_in,
                              void* d_out, int out_size, void* d_ws, size_t ws_size,
                              hipStream_t stream) {
  const float* q = (const float*)d_in[0];
  const float* k = (const float*)d_in[1];
  const float* v = (const float*)d_in[2];
  float* o = (float*)d_out;
  const int bh = in_sizes[0] / (N_CTX * DIM);  // B*H = 32
  dim3 grid(N_CTX / QBLK, bh);
  hipLaunchKernelGGL(fa_fwd, grid, dim3(512), 0, stream, q, k, v, o);
}

// Round 4
// 437.779 us; speedup vs baseline: 1.7917x; 1.0032x over previous
//
#include <hip/hip_runtime.h>
#include <hip/hip_bf16.h>

typedef __attribute__((ext_vector_type(8))) short short8;
typedef __attribute__((ext_vector_type(8))) unsigned short ushort8;
typedef __attribute__((ext_vector_type(4))) unsigned short usv4;
typedef __attribute__((ext_vector_type(4))) float f32x4;

#define MFMA16(a, b, c) __builtin_amdgcn_mfma_f32_16x16x32_bf16((a), (b), (c), 0, 0, 0)

static constexpr int N_CTX = 4096;
static constexpr int DIM = 64;
static constexpr int QBLK = 128;  // 8 waves x 16 rows
static constexpr int KVB = 64;
static constexpr int NT = N_CTX / KVB;

__device__ __forceinline__ unsigned short f2bf(float f) {
  union { __hip_bfloat16 h; unsigned short u; } cv;
  cv.h = __float2bfloat16(f);
  return cv.u;
}
__device__ __forceinline__ float bf2f(unsigned short u) {
  union { unsigned int i; float f; } cv;
  cv.i = ((unsigned int)u) << 16;
  return cv.f;
}

// 8 waves. Wave w owns Q rows [qb*128 + w*16, +16).
// S^T via mfma(A=K, B=Q): softmax is in-lane (q = li domain).
// LDS bf16 tiles, 16B-chunk XOR swizzle: chunk ^= (row & 7).
// Staging: thread (w,lane) owns K/V row `lane`, d-cols [w*8, w*8+8)
// (row=lane keeps lane>>3 spanning 0..7 -> V scalar-store swizzle works;
//  round-3's tid>>3 mapping made it wave-constant -> 6.7e7 conflicts).
__global__ __launch_bounds__(512, 4) void fa_fwd(
    const float* __restrict__ Q, const float* __restrict__ K,
    const float* __restrict__ V, float* __restrict__ O) {
  __shared__ unsigned short K_lds[KVB * DIM];    // [kv][d]
  __shared__ unsigned short V_lds[DIM * KVB];    // [d][kv] transposed
  __shared__ unsigned short P_lds[8][16 * KVB];  // per-wave [q][kv]

  const int tid = threadIdx.x;
  const int wave = tid >> 6;
  const int lane = tid & 63;
  const int g = lane >> 4;   // 0..3
  const int li = lane & 15;  // 0..15

  const size_t bh = blockIdx.y;
  const int qb = blockIdx.x;
  const float* Qb = Q + bh * N_CTX * DIM;
  const float* Kb = K + bh * N_CTX * DIM;
  const float* Vb = V + bh * N_CTX * DIM;
  float* Ob = O + bh * N_CTX * DIM;

  // ---- Q fragments (B-operand layout == A layout); fold 1/64 scale in ----
  short8 aq0, aq1;
  {
    const float* qr = Qb + (size_t)(qb * QBLK + wave * 16 + li) * DIM;
    f32x4 q0 = *(const f32x4*)(qr + g * 8);
    f32x4 q1 = *(const f32x4*)(qr + g * 8 + 4);
    f32x4 q2 = *(const f32x4*)(qr + 32 + g * 8);
    f32x4 q3 = *(const f32x4*)(qr + 32 + g * 8 + 4);
    const float scale = 1.0f / 64.0f;
#pragma unroll
    for (int j = 0; j < 4; ++j) {
      aq0[j] = (short)f2bf(q0[j] * scale);
      aq0[j + 4] = (short)f2bf(q1[j] * scale);
      aq1[j] = (short)f2bf(q2[j] * scale);
      aq1[j + 4] = (short)f2bf(q3[j] * scale);
    }
  }

  f32x4 acc[4] = {{0.f, 0.f, 0.f, 0.f}, {0.f, 0.f, 0.f, 0.f},
                  {0.f, 0.f, 0.f, 0.f}, {0.f, 0.f, 0.f, 0.f}};
  float m_st = -1e30f;  // per q = li (uniform across g groups)
  float l_st = 0.f;

  // ---- prologue: prefetch tile 0 into registers ----
  const float* kp0 = Kb + (size_t)lane * DIM + wave * 8;
  const float* vp0 = Vb + (size_t)lane * DIM + wave * 8;
  f32x4 kf0 = *(const f32x4*)kp0, kf1 = *(const f32x4*)(kp0 + 4);
  f32x4 vf0 = *(const f32x4*)vp0, vf1 = *(const f32x4*)(vp0 + 4);

  for (int t = 0; t < NT; ++t) {
    // ---- stage tile t from prefetch registers ----
    {
      ushort8 kk;
#pragma unroll
      for (int j = 0; j < 4; ++j) {
        kk[j] = f2bf(kf0[j]);
        kk[j + 4] = f2bf(kf1[j]);
      }
      *(ushort8*)((char*)K_lds + lane * 128 + ((wave ^ (lane & 7)) * 16)) = kk;
      float vv[8] = {vf0[0], vf0[1], vf0[2], vf0[3],
                     vf1[0], vf1[1], vf1[2], vf1[3]};
#pragma unroll
      for (int j = 0; j < 8; ++j) {
        const int d = wave * 8 + j;  // fixed d per instr; lane>>3 spans 0..7
        *(unsigned short*)((char*)V_lds + d * 128 +
                           (((lane >> 3) ^ (d & 7)) * 16) + (lane & 7) * 2) =
            f2bf(vv[j]);
      }
    }
    __syncthreads();

    // ---- issue prefetch for tile t+1 (completes under compute) ----
    if (t + 1 < NT) {
      const float* kp = Kb + ((size_t)(t + 1) * KVB + lane) * DIM + wave * 8;
      const float* vp = Vb + ((size_t)(t + 1) * KVB + lane) * DIM + wave * 8;
      kf0 = *(const f32x4*)kp;
      kf1 = *(const f32x4*)(kp + 4);
      vf0 = *(const f32x4*)vp;
      vf1 = *(const f32x4*)(vp + 4);
    }

    // ---- S^T = K·Q^T : lane holds S[q=li][kv=16*ct+4*g+r] ----
    f32x4 s[4];
#pragma unroll
    for (int ct = 0; ct < 4; ++ct) {
      const int krow = ct * 16 + li;
      const char* kp2 = (const char*)K_lds + krow * 128;
      short8 b0 = *(const short8*)(kp2 + ((g ^ (krow & 7)) * 16));
      short8 b1 = *(const short8*)(kp2 + (((4 + g) ^ (krow & 7)) * 16));
      f32x4 z = {0.f, 0.f, 0.f, 0.f};
      z = MFMA16(b0, aq0, z);
      z = MFMA16(b1, aq1, z);
      s[ct] = z;
    }

    // ---- in-lane online softmax (q = li) ----
    float mx = s[0][0];
#pragma unroll
    for (int ct = 0; ct < 4; ++ct)
#pragma unroll
      for (int r = 0; r < 4; ++r) mx = fmaxf(mx, s[ct][r]);
    mx = fmaxf(mx, __shfl_xor(mx, 16));
    mx = fmaxf(mx, __shfl_xor(mx, 32));
    const float mn = fmaxf(m_st, mx);
    const float alpha = __expf(m_st - mn);
    m_st = mn;

    float ps = 0.f;
#pragma unroll
    for (int ct = 0; ct < 4; ++ct) {
      usv4 u;
#pragma unroll
      for (int r = 0; r < 4; ++r) {
        const unsigned short uu = f2bf(__expf(s[ct][r] - mn));
        u[r] = uu;
        ps += bf2f(uu);  // sum ROUNDED P so numerator/denominator match
      }
      // kv = 16*ct + 4*g + r -> chunk = 2*ct + (g>>1), byte-in-chunk 8*(g&1)+2r
      *(usv4*)((char*)P_lds[wave] + li * 128 +
               (((2 * ct + (g >> 1)) ^ (li & 7)) * 16) + 8 * (g & 1)) = u;
    }
    ps += __shfl_xor(ps, 16);
    ps += __shfl_xor(ps, 32);
    l_st = alpha * l_st + ps;

    // rescale acc: need alpha for q rows g*4+r (it lives at lane with li=g*4+r)
    float ar[4];
#pragma unroll
    for (int r = 0; r < 4; ++r) ar[r] = __shfl(alpha, (lane & 48) | (g * 4 + r));
#pragma unroll
    for (int dt = 0; dt < 4; ++dt)
#pragma unroll
      for (int r = 0; r < 4; ++r) acc[dt][r] *= ar[r];

    // ---- O += P·V  (A = P rows q=li, B = V^T tile) ----
    const char* pp = (const char*)P_lds[wave] + li * 128;
    short8 pa0 = *(const short8*)(pp + ((g ^ (li & 7)) * 16));
    short8 pa1 = *(const short8*)(pp + (((4 + g) ^ (li & 7)) * 16));
#pragma unroll
    for (int dt = 0; dt < 4; ++dt) {
      const int d = dt * 16 + li;
      const char* vp2 = (const char*)V_lds + d * 128;
      short8 b0 = *(const short8*)(vp2 + ((g ^ (d & 7)) * 16));
      short8 b1 = *(const short8*)(vp2 + (((4 + g) ^ (d & 7)) * 16));
      acc[dt] = MFMA16(pa0, b0, acc[dt]);
      acc[dt] = MFMA16(pa1, b1, acc[dt]);
    }
    __syncthreads();
  }

  // ---- epilogue: O / max(l, eps); l lives at lane with li = q row ----
  float lr[4];
#pragma unroll
  for (int r = 0; r < 4; ++r) lr[r] = __shfl(l_st, (lane & 48) | (g * 4 + r));
#pragma unroll
  for (int r = 0; r < 4; ++r) {
    const float inv = 1.0f / fmaxf(lr[r], 1e-6f);
    float* orow = Ob + (size_t)(qb * QBLK + wave * 16 + g * 4 + r) * DIM + li;
#pragma unroll
    for (int dt = 0; dt < 4; ++dt) orow[dt * 16] = acc[dt][r] * inv;
  }
}

extern "C" void kernel_launch(void* const* d_in, const int* in_sizes, int n_in,
                              void* d_out, int out_size, void* d_ws, size_t ws_size,
                              hipStream_t stream) {
  const float* q = (const float*)d_in[0];
  const float* k = (const float*)d_in[1];
  const float* v = (const float*)d_in[2];
  float* o = (float*)d_out;
  const int bh = in_sizes[0] / (N_CTX * DIM);  // B*H = 32
  dim3 grid(N_CTX / QBLK, bh);
  hipLaunchKernelGGL(fa_fwd, grid, dim3(512), 0, stream, q, k, v, o);
}

// Round 5
// 321.788 us; speedup vs baseline: 2.4375x; 1.3605x over previous
//
#include <hip/hip_runtime.h>
#include <hip/hip_bf16.h>

typedef __attribute__((ext_vector_type(8))) short short8;
typedef __attribute__((ext_vector_type(4))) float f32x4;
typedef __attribute__((ext_vector_type(16))) float f32x16;

#define MFMA32(a, b, c) __builtin_amdgcn_mfma_f32_32x32x16_bf16((a), (b), (c), 0, 0, 0)

static constexpr int N_CTX = 4096;
static constexpr int DIM = 64;
static constexpr int QBLK = 256;  // 8 waves x 32 q-rows
static constexpr int KVB = 64;
static constexpr int NT = N_CTX / KVB;

__device__ __forceinline__ unsigned short f2bf(float f) {
  union { __hip_bfloat16 h; unsigned short u; } cv;
  cv.h = __float2bfloat16(f);
  return cv.u;
}
__device__ __forceinline__ float bfbits(unsigned u) {
  union { unsigned i; float f; } cv;
  cv.i = u;
  return cv.f;
}
__device__ __forceinline__ unsigned pkbf(float a, float b) {
  return (((unsigned)f2bf(b)) << 16) | (unsigned)f2bf(a);
}

// 8 waves x 32 q-rows. S^T = mfma(A=K, B=Q) (32x32x16): lane holds
// S[q=lane&31][kv=(r&3)+8*(r>>2)+4*hi+32*kb] -> softmax fully in-lane.
// PV as mfma(A=V^T, B=P): acc = O^T[d][q=lane&31] -> rescale in-lane.
// LDS: double-buffered K[kv][d] + V^T[d][kv], 16B-chunk swizzle ^(row&7).
// One barrier per tile: barrier(t) separates compute(t-1) from stage(t+1).
__global__ __launch_bounds__(512, 4) void fa_fwd(
    const float* __restrict__ Q, const float* __restrict__ K,
    const float* __restrict__ V, float* __restrict__ O) {
  __shared__ unsigned short K_lds[2][KVB * DIM];
  __shared__ unsigned short V_lds[2][DIM * KVB];

  const int tid = threadIdx.x;
  const int wave = tid >> 6;
  const int lane = tid & 63;
  const int ql = lane & 31;
  const int hi = lane >> 5;

  const size_t bh = blockIdx.y;
  const int qb = blockIdx.x;
  const float* Qb = Q + bh * N_CTX * DIM;
  const float* Kb = K + bh * N_CTX * DIM;
  const float* Vb = V + bh * N_CTX * DIM;
  float* Ob = O + bh * N_CTX * DIM;

  // ---- Q B-frags: lane holds Q[q=ql][d=16*dc+8*hi+j] * (1/64) ----
  short8 qf[4];
  {
    const float* qr = Qb + (size_t)(qb * QBLK + wave * 32 + ql) * DIM + hi * 8;
    const float sc = 1.0f / 64.0f;
#pragma unroll
    for (int dc = 0; dc < 4; ++dc) {
      f32x4 a = *(const f32x4*)(qr + dc * 16);
      f32x4 b = *(const f32x4*)(qr + dc * 16 + 4);
#pragma unroll
      for (int j = 0; j < 4; ++j) {
        qf[dc][j] = (short)f2bf(a[j] * sc);
        qf[dc][j + 4] = (short)f2bf(b[j] * sc);
      }
    }
  }

  f32x16 acc0 = {};  // O^T[d=(r&3)+8*(r>>2)+4*hi][q=ql]
  f32x16 acc1 = {};  // d + 32
  float m_st = -1e30f, l_st = 0.f;

  // ---- prologue prefetch: thread (wave,lane) owns row=lane, d [wave*8,+8) ----
  const float* kpf = Kb + (size_t)lane * DIM + wave * 8;
  const float* vpf = Vb + (size_t)lane * DIM + wave * 8;
  f32x4 kf0 = *(const f32x4*)kpf, kf1 = *(const f32x4*)(kpf + 4);
  f32x4 vf0 = *(const f32x4*)vpf, vf1 = *(const f32x4*)(vpf + 4);

  for (int t = 0; t < NT; ++t) {
    unsigned short* Kl = K_lds[t & 1];
    unsigned short* Vl = V_lds[t & 1];
    // ---- stage tile t (overlaps other waves' compute of t-1) ----
    {
      union { short8 v; unsigned short e[8]; } kk;
#pragma unroll
      for (int j = 0; j < 4; ++j) {
        kk.e[j] = f2bf(kf0[j]);
        kk.e[j + 4] = f2bf(kf1[j]);
      }
      *(short8*)((char*)Kl + lane * 128 + ((wave ^ (lane & 7)) * 16)) = kk.v;
      float vv[8] = {vf0[0], vf0[1], vf0[2], vf0[3],
                     vf1[0], vf1[1], vf1[2], vf1[3]};
#pragma unroll
      for (int j = 0; j < 8; ++j) {
        const int d = wave * 8 + j;  // fixed d per instr; lane>>3 spans 0..7
        *(unsigned short*)((char*)Vl + d * 128 +
                           (((lane >> 3) ^ (d & 7)) * 16) + (lane & 7) * 2) =
            f2bf(vv[j]);
      }
    }
    if (t + 1 < NT) {  // issue next-tile loads; land under compute
      const float* kp = Kb + ((size_t)(t + 1) * KVB + lane) * DIM + wave * 8;
      const float* vp = Vb + ((size_t)(t + 1) * KVB + lane) * DIM + wave * 8;
      kf0 = *(const f32x4*)kp;
      kf1 = *(const f32x4*)(kp + 4);
      vf0 = *(const f32x4*)vp;
      vf1 = *(const f32x4*)(vp + 4);
    }
    __syncthreads();

    // ---- S^T = K·Q^T : 8 MFMA ----
    f32x16 s0 = {}, s1 = {};
    {
      const int kr0 = ql, kr1 = 32 + ql;
      const char* ka0 = (const char*)Kl + kr0 * 128;
      const char* ka1 = (const char*)Kl + kr1 * 128;
#pragma unroll
      for (int dc = 0; dc < 4; ++dc) {
        short8 f0 = *(const short8*)(ka0 + (((2 * dc + hi) ^ (kr0 & 7)) * 16));
        short8 f1 = *(const short8*)(ka1 + (((2 * dc + hi) ^ (kr1 & 7)) * 16));
        s0 = MFMA32(f0, qf[dc], s0);
        s1 = MFMA32(f1, qf[dc], s1);
      }
    }

    // ---- in-lane online softmax (q = ql); T13 defer-max THR=8 ----
    float mx = fmaxf(s0[0], s1[0]);
#pragma unroll
    for (int r = 1; r < 16; ++r) mx = fmaxf(mx, fmaxf(s0[r], s1[r]));
    mx = fmaxf(mx, __shfl_xor(mx, 32));
    if (!__all(mx <= m_st + 8.f)) {
      const float mn = fmaxf(m_st, mx);
      const float al = __expf(m_st - mn);
      m_st = mn;
      l_st *= al;
#pragma unroll
      for (int r = 0; r < 16; ++r) {
        acc0[r] *= al;
        acc1[r] *= al;
      }
    }
#pragma unroll
    for (int r = 0; r < 16; ++r) {
      s0[r] = __expf(s0[r] - m_st);
      s1[r] = __expf(s1[r] - m_st);
    }

    // ---- pack P to bf16 words; l from ROUNDED values ----
    unsigned w0[4][2], w1[4][2];
#pragma unroll
    for (int g = 0; g < 4; ++g) {
      w0[g][0] = pkbf(s0[4 * g + 0], s0[4 * g + 1]);
      w0[g][1] = pkbf(s0[4 * g + 2], s0[4 * g + 3]);
      w1[g][0] = pkbf(s1[4 * g + 0], s1[4 * g + 1]);
      w1[g][1] = pkbf(s1[4 * g + 2], s1[4 * g + 3]);
    }
    float ps = 0.f;
#pragma unroll
    for (int g = 0; g < 4; ++g)
#pragma unroll
      for (int e = 0; e < 2; ++e)
        ps += bfbits(w0[g][e] << 16) + bfbits(w0[g][e] & 0xffff0000u) +
              bfbits(w1[g][e] << 16) + bfbits(w1[g][e] & 0xffff0000u);
    ps += __shfl_xor(ps, 32);
    l_st += ps;

    // ---- build PV B-frags: keep own-half words, swap the rest (T12) ----
#define PACKKC(W, GA, OUT)                                           \
  {                                                                  \
    unsigned k0 = hi ? W[(GA) + 1][0] : W[GA][0];                    \
    unsigned k1 = hi ? W[(GA) + 1][1] : W[GA][1];                    \
    unsigned x0 = hi ? W[GA][0] : W[(GA) + 1][0];                    \
    unsigned x1 = hi ? W[GA][1] : W[(GA) + 1][1];                    \
    unsigned r0 = (unsigned)__shfl_xor((int)x0, 32);                 \
    unsigned r1 = (unsigned)__shfl_xor((int)x1, 32);                 \
    union { short8 v; unsigned u[4]; } fu;                           \
    fu.u[0] = hi ? r0 : k0;                                          \
    fu.u[1] = hi ? r1 : k1;                                          \
    fu.u[2] = hi ? k0 : r0;                                          \
    fu.u[3] = hi ? k1 : r1;                                          \
    OUT = fu.v;                                                      \
  }
    short8 bfr0, bfr1, bfr2, bfr3;
    PACKKC(w0, 0, bfr0)
    PACKKC(w0, 2, bfr1)
    PACKKC(w1, 0, bfr2)
    PACKKC(w1, 2, bfr3)
#undef PACKKC

    // ---- O^T += V^T·P : 8 MFMA ----
    {
      const int vr0 = ql, vr1 = 32 + ql;
      const char* va0 = (const char*)Vl + vr0 * 128;
      const char* va1 = (const char*)Vl + vr1 * 128;
#pragma unroll
      for (int kc = 0; kc < 4; ++kc) {
        short8 a0 = *(const short8*)(va0 + (((2 * kc + hi) ^ (vr0 & 7)) * 16));
        short8 a1 = *(const short8*)(va1 + (((2 * kc + hi) ^ (vr1 & 7)) * 16));
        const short8 bb = (kc == 0) ? bfr0 : (kc == 1) ? bfr1
                          : (kc == 2) ? bfr2 : bfr3;
        acc0 = MFMA32(a0, bb, acc0);
        acc1 = MFMA32(a1, bb, acc1);
      }
    }
  }

  // ---- epilogue: O[q][d] = acc/l ----
  const float inv = 1.0f / fmaxf(l_st, 1e-6f);
  float* orow = Ob + (size_t)(qb * QBLK + wave * 32 + ql) * DIM;
#pragma unroll
  for (int r = 0; r < 16; ++r) {
    const int d = (r & 3) + 8 * (r >> 2) + 4 * hi;
    orow[d] = acc0[r] * inv;
    orow[d + 32] = acc1[r] * inv;
  }
}

extern "C" void kernel_launch(void* const* d_in, const int* in_sizes, int n_in,
                              void* d_out, int out_size, void* d_ws, size_t ws_size,
                              hipStream_t stream) {
  const float* q = (const float*)d_in[0];
  const float* k = (const float*)d_in[1];
  const float* v = (const float*)d_in[2];
  float* o = (float*)d_out;
  const int bh = in_sizes[0] / (N_CTX * DIM);  // B*H = 32
  dim3 grid(N_CTX / QBLK, bh);
  hipLaunchKernelGGL(fa_fwd, grid, dim3(512), 0, stream, q, k, v, o);
}